// Round 7
// baseline (319.279 us; speedup 1.0000x reference)
//
#include <hip/hip_runtime.h>
#include <stdint.h>

#define S_LEN 256
#define DIM   128
#define EPSL  1e-5f

typedef __bf16 bf16x8 __attribute__((ext_vector_type(8)));
typedef float  f32x4  __attribute__((ext_vector_type(4)));

__device__ __forceinline__ unsigned short f2bf_bits(float f) {
  union { float f; unsigned int u; } v; v.f = f;
  unsigned int r = v.u + 0x7fffu + ((v.u >> 16) & 1u);   // RTNE (init paths)
  return (unsigned short)(r >> 16);
}
__device__ __forceinline__ float bf2f_bits(unsigned short b) {
  union { float f; unsigned int u; } v; v.u = ((unsigned int)b) << 16; return v.f;
}
// Hot-path bf16 round-half-up: 2 VALU ops.
__device__ __forceinline__ unsigned f2bf_rhu(float f) {
  return (__float_as_uint(f) + 0x8000u) >> 16;
}
// Pack two floats -> (bf16 lo, bf16 hi) in one u32: 2 adds + 1 v_perm.
__device__ __forceinline__ unsigned pack_rhu(float lo, float hi) {
  return __builtin_amdgcn_perm(__float_as_uint(hi) + 0x8000u,
                               __float_as_uint(lo) + 0x8000u, 0x07060302u);
}
// tanh(x) = 1 - 2/(e^{2x}+1): ~1e-6 rel err, exact at +-inf.
__device__ __forceinline__ float tanh_fast(float x) {
  float e = __expf(2.f * x);
  return 1.f - 2.f * __builtin_amdgcn_rcpf(e + 1.f);
}

// VALU cross-lane via DPP rotation; 16-lane reduce visible on all lanes.
template<int CTRL>
__device__ __forceinline__ float dpp_rot_add(float v) {
  int r = __builtin_amdgcn_update_dpp(0, __float_as_int(v), CTRL, 0xF, 0xF, true);
  return v + __int_as_float(r);
}
template<int CTRL>
__device__ __forceinline__ float dpp_rot_max(float v) {
  int r = __builtin_amdgcn_update_dpp(0, __float_as_int(v), CTRL, 0xF, 0xF, true);
  return fmaxf(v, __int_as_float(r));
}
__device__ __forceinline__ float dpp_sum16(float v) {
  v = dpp_rot_add<0x124>(v); v = dpp_rot_add<0x128>(v);
  v = dpp_rot_add<0x39>(v);  v = dpp_rot_add<0x4E>(v);
  return v;
}
__device__ __forceinline__ float dpp_max16(float v) {
  v = dpp_rot_max<0x124>(v); v = dpp_rot_max<0x128>(v);
  v = dpp_rot_max<0x39>(v);  v = dpp_rot_max<0x4E>(v);
  return v;
}
template<int CTRL>
__device__ __forceinline__ void red_level7(float& s, float& sq, float* d) {
  s  = dpp_rot_add<CTRL>(s);
  sq = dpp_rot_add<CTRL>(sq);
#pragma unroll
  for (int j = 0; j < 5; j++) d[j] = dpp_rot_add<CTRL>(d[j]);
}
template<int JJ>
__device__ __forceinline__ float bcast16(float v) {
  int r = __builtin_amdgcn_ds_swizzle(__float_as_int(v), (JJ << 5) | 0x10);
  return __int_as_float(r);
}

union Frag8 { unsigned short us[8]; bf16x8 v; int4 i4; };

// ============================ Kernel 1: pre-pass ============================
// xproj[b][t][n] = emb[x[b,t]] @ Wih1^T + (bih1+bhh1), bf16, stored in the
// serial kernel's D-fragment order: ws[((t*64+bb)*128 + n)*16 + row].
// Grid: 64 bb x 16 t-chunks = 1024 blocks x 512 thr (8 waves, one n-tile each).
__global__ __launch_bounds__(512, 2)
void xproj_pre(const int* __restrict__ x, const float* __restrict__ emb,
               const float* __restrict__ Wih1, const float* __restrict__ bih1,
               const float* __restrict__ bhh1, unsigned short* __restrict__ ws)
{
  __shared__ __align__(16) unsigned short e_s[16 * 128];
  const int tid  = threadIdx.x;
  const int wave = tid >> 6;
  const int lane = tid & 63;
  const int l15  = lane & 15;
  const int q    = lane >> 4;
  const int bb   = blockIdx.x >> 4;    // 0..63
  const int tc   = blockIdx.x & 15;    // 0..15
  const int r0   = bb * 16;

  const int n1 = wave * 16 + l15;
  const float bias1v = bih1[n1] + bhh1[n1];
  bf16x8 wih[4];
#pragma unroll
  for (int kt = 0; kt < 4; kt++) {
    int k0 = kt * 32 + q * 8;
    Frag8 fa;
#pragma unroll
    for (int j = 0; j < 8; j++) fa.us[j] = f2bf_bits(Wih1[n1 * DIM + k0 + j]);
    wih[kt] = fa.v;
  }

  for (int tt = 0; tt < 16; tt++) {
    const int t = tc * 16 + tt;
    if (tid < 256) {                   // stage e rows for this t (swizzled)
      int m = tid >> 4, oct = tid & 15;
      int xid = x[(size_t)(r0 + m) * S_LEN + t];
      const float* pe = emb + (size_t)xid * DIM + oct * 8;
      float4 lv0 = *(const float4*)pe;
      float4 lv1 = *(const float4*)(pe + 4);
      int4 pk;
      pk.x = pack_rhu(lv0.x, lv0.y); pk.y = pack_rhu(lv0.z, lv0.w);
      pk.z = pack_rhu(lv1.x, lv1.y); pk.w = pack_rhu(lv1.z, lv1.w);
      *(int4*)&e_s[m * 128 + ((oct ^ m) & 15) * 8] = pk;
    }
    __syncthreads();
    f32x4 a = {bias1v, bias1v, bias1v, bias1v};
#pragma unroll
    for (int kt = 0; kt < 4; kt++) {
      int sw = (((kt * 4 + q) ^ l15) & 15) * 8;
      bf16x8 ae = *(const bf16x8*)&e_s[l15 * 128 + sw];
      a = __builtin_amdgcn_mfma_f32_16x16x32_bf16(ae, wih[kt], a, 0, 0, 0);
    }
    uint2 st;                          // rows q*4..q*4+3, col n1
    st.x = pack_rhu(a[0], a[1]); st.y = pack_rhu(a[2], a[3]);
    *(uint2*)&ws[(((size_t)t * 64 + bb) * 128 + n1) * 16 + q * 4] = st;
    __syncthreads();
  }
}

// ============================ Kernel 2: serial RNN ==========================
// 8 homogeneous waves; per wave per step: 8 MFMA (h@Whh hi+lo) + one 8B global
// prefetch of its xproj fragment (2 steps ahead) + 4-tanh epilogue.
// Waves 0-3 also carry LN1/RNN2/LN2/pool (off the serial chain).
__global__ __launch_bounds__(512, 2)
void rnn_serial(const unsigned short* __restrict__ xp,
                const float* __restrict__ Whh1,
                const float* __restrict__ g1,  const float* __restrict__ be1,
                const float* __restrict__ Wih2, const float* __restrict__ bih2,
                const float* __restrict__ Whh2, const float* __restrict__ bhh2,
                const float* __restrict__ g2,  const float* __restrict__ be2,
                float* __restrict__ out)
{
  __shared__ __align__(16) unsigned short h_bf[2][16 * 128];   // 8 KB total
  const int tid  = threadIdx.x;
  const int wave = tid >> 6;
  const int lane = tid & 63;
  const int bb   = blockIdx.x;
  const int r0   = bb * 16;
  const int l15  = lane & 15;
  const int q    = lane >> 4;

  for (int i = tid; i < 16 * 128; i += 512) h_bf[1][i] = 0;   // h_{-1} = 0

  const int n1 = wave * 16 + l15;
  bf16x8 whi[4], wlo[4];
#pragma unroll
  for (int kt = 0; kt < 4; kt++) {
    int k0 = kt * 32 + q * 8;
    Frag8 fh, fl;
#pragma unroll
    for (int j = 0; j < 8; j++) {
      float w = Whh1[n1 * DIM + k0 + j];
      unsigned short hi = f2bf_bits(w);
      fh.us[j] = hi;
      fl.us[j] = f2bf_bits(w - bf2f_bits(hi));     // split-bf16 compensation
    }
    whi[kt] = fh.v; wlo[kt] = fl.v;
  }
  // xproj element offset for this lane at step t: t*131072 + xofs
  const size_t xofs = ((size_t)bb * 128 + n1) * 16 + q * 4;

  const bool ln_role = (wave < 4);
  float w2g[5][8], Gs[5], Bs[5], wrow[5];
  float t2_l = 0.f, g2_l = 0.f, be2_l = 0.f, validf = 0.f;
  float h2rep[5], pool_l = 0.f;
  int myrow = 0;
  if (ln_role) {
    myrow = wave * 4 + q;
    int coct = (l15 ^ myrow) & 15;
#pragma unroll
    for (int j = 0; j < 8; j++) {
      int c = coct * 8 + j;
      float gc = g1[c];
#pragma unroll
      for (int jj = 0; jj < 5; jj++) w2g[jj][j] = Wih2[jj * DIM + c] * gc;
    }
#pragma unroll
    for (int jj = 0; jj < 5; jj++) { Gs[jj] = 0.f; Bs[jj] = 0.f; }
    for (int c = 0; c < DIM; c++) {
      float gc = g1[c], bc = be1[c];
#pragma unroll
      for (int jj = 0; jj < 5; jj++) {
        float w = Wih2[jj * DIM + c];
        Gs[jj] += w * gc; Bs[jj] += w * bc;
      }
    }
    validf = (l15 < 5) ? 1.f : 0.f;
    if (l15 < 5) {
      t2_l = bih2[l15] + bhh2[l15];
      g2_l = g2[l15]; be2_l = be2[l15];
#pragma unroll
      for (int jj = 0; jj < 5; jj++) wrow[jj] = Whh2[l15 * 5 + jj];
    } else {
#pragma unroll
      for (int jj = 0; jj < 5; jj++) wrow[jj] = 0.f;
    }
#pragma unroll
    for (int jj = 0; jj < 5; jj++) h2rep[jj] = 0.f;
  }

  uint2 pfx[2];                        // xproj prefetch ring, 2 steps deep
  pfx[0] = *(const uint2*)&xp[xofs];
  pfx[1] = *(const uint2*)&xp[xofs + 131072];
  __syncthreads();

#pragma unroll 2                       // static parities for pfx ring
  for (int t = 0; t <= S_LEN; t++) {
    if (t < S_LEN) {                   // ---- serial core: h_t for my n-tile
      uint2 cur = pfx[t & 1];
      if (t + 2 < S_LEN)               // refill for t+2 (off-chain, vmcnt)
        pfx[t & 1] = *(const uint2*)&xp[xofs + (size_t)(t + 2) * 131072];
      const int rb = (t + 1) & 1;      // h_{t-1}
      f32x4 ah = {0.f, 0.f, 0.f, 0.f}, al = {0.f, 0.f, 0.f, 0.f};
#pragma unroll
      for (int kt = 0; kt < 4; kt++) {
        int sw = (((kt * 4 + q) ^ l15) & 15) * 8;
        bf16x8 ahf = *(const bf16x8*)&h_bf[rb][l15 * 128 + sw];
        ah = __builtin_amdgcn_mfma_f32_16x16x32_bf16(ahf, whi[kt], ah, 0, 0, 0);
        al = __builtin_amdgcn_mfma_f32_16x16x32_bf16(ahf, wlo[kt], al, 0, 0, 0);
      }
      float xq[4];                     // unpack 4 bf16 (rows q*4..+3)
      xq[0] = __uint_as_float(cur.x << 16);
      xq[1] = __uint_as_float(cur.x & 0xffff0000u);
      xq[2] = __uint_as_float(cur.y << 16);
      xq[3] = __uint_as_float(cur.y & 0xffff0000u);
      const int wb = t & 1;
      const int c = n1;                // col = wave*16 + l15
      const int oct = c >> 3;
#pragma unroll
      for (int r = 0; r < 4; r++) {    // D-layout: row = q*4 + r, col = l15
        int row = q * 4 + r;
        float av = ah[r] + al[r] + xq[r];
        h_bf[wb][row * 128 + ((oct ^ row) & 15) * 8 + (c & 7)] =
            (unsigned short)f2bf_rhu(tanh_fast(av));
      }
    }
    if (ln_role && t >= 1) {           // ---- LN role on h_{t-1}
      const int hb = (t - 1) & 1;
      Frag8 hr;
      hr.i4 = *(const int4*)&h_bf[hb][myrow * 128 + l15 * 8];
      float s = 0.f, sq = 0.f, d[5] = {0, 0, 0, 0, 0};
#pragma unroll
      for (int j = 0; j < 8; j++) {
        float v = bf2f_bits(hr.us[j]);
        s += v; sq += v * v;
#pragma unroll
        for (int jj = 0; jj < 5; jj++) d[jj] = fmaf(w2g[jj][j], v, d[jj]);
      }
      red_level7<0x124>(s, sq, d);
      red_level7<0x128>(s, sq, d);
      red_level7<0x39>(s, sq, d);
      red_level7<0x4E>(s, sq, d);
      float mean = s * (1.f / 128.f);
      float var  = sq * (1.f / 128.f) - mean * mean;
      float rstd = rsqrtf(var + EPSL);
      float p[5];
#pragma unroll
      for (int jj = 0; jj < 5; jj++)
        p[jj] = rstd * (d[jj] - mean * Gs[jj]) + Bs[jj];
      float psel = (l15 == 0) ? p[0] : (l15 == 1) ? p[1] :
                   (l15 == 2) ? p[2] : (l15 == 3) ? p[3] : p[4];
      float a = psel + t2_l;
#pragma unroll
      for (int jj = 0; jj < 5; jj++) a = fmaf(wrow[jj], h2rep[jj], a);
      float xn = tanh_fast(a);
      h2rep[0] = bcast16<0>(xn); h2rep[1] = bcast16<1>(xn);
      h2rep[2] = bcast16<2>(xn); h2rep[3] = bcast16<3>(xn);
      h2rep[4] = bcast16<4>(xn);
      float s2 = dpp_sum16(xn * validf) * 0.2f;
      float dd = xn - s2;
      float v2 = dpp_sum16(dd * dd * validf) * 0.2f;
      float r2 = rsqrtf(v2 + EPSL);
      pool_l += dd * r2 * g2_l + be2_l;
    }
    // Raw barrier: drain LDS only; xproj prefetch stays in flight.
    asm volatile("s_waitcnt lgkmcnt(0)\n\ts_barrier" ::: "memory");
  }

  if (ln_role) {
    float lg = pool_l * (1.f / 256.f);
    float mx = dpp_max16((l15 < 5) ? lg : -3.0e38f);
    float e  = (l15 < 5) ? __expf(lg - mx) : 0.f;
    float sm = dpp_sum16(e);
    if (l15 < 5) out[(size_t)(r0 + myrow) * 5 + l15] = e / sm;
  }
}

// ===================== Fallback: R6 fused single kernel =====================
__global__ __launch_bounds__(512, 2)
void rnn_fused_fb(const int* __restrict__ x, const float* __restrict__ emb,
                  const float* __restrict__ Wih1, const float* __restrict__ bih1,
                  const float* __restrict__ Whh1, const float* __restrict__ bhh1,
                  const float* __restrict__ g1, const float* __restrict__ be1,
                  const float* __restrict__ Wih2, const float* __restrict__ bih2,
                  const float* __restrict__ Whh2, const float* __restrict__ bhh2,
                  const float* __restrict__ g2, const float* __restrict__ be2,
                  float* __restrict__ out)
{
  __shared__ __align__(16) unsigned short h_bf[2][16 * 128];
  __shared__ __align__(16) unsigned short e_bf[2][16 * 128];
  __shared__ int x_tile[16 * 256];

  const int tid  = threadIdx.x;
  const int wave = tid >> 6;
  const int lane = tid & 63;
  const int r0   = blockIdx.x * 16;
  const int l15  = lane & 15;
  const int q    = lane >> 4;

  for (int i = tid; i < 16 * 256; i += 512)
    x_tile[i] = x[(size_t)(r0 + (i >> 8)) * S_LEN + (i & 255)];
  for (int i = tid; i < 16 * 128; i += 512) h_bf[1][i] = 0;

  const int n1 = wave * 16 + l15;
  const float bias1v = bih1[n1] + bhh1[n1];
  bf16x8 whi[4], wlo[4], wih[4];
#pragma unroll
  for (int kt = 0; kt < 4; kt++) {
    int k0 = kt * 32 + q * 8;
    Frag8 fh, fl, fa;
#pragma unroll
    for (int j = 0; j < 8; j++) {
      float w = Whh1[n1 * DIM + k0 + j];
      unsigned short hi = f2bf_bits(w);
      fh.us[j] = hi;
      fl.us[j] = f2bf_bits(w - bf2f_bits(hi));
      fa.us[j] = f2bf_bits(Wih1[n1 * DIM + k0 + j]);
    }
    whi[kt] = fh.v; wlo[kt] = fl.v; wih[kt] = fa.v;
  }

  const bool ln_role = (wave < 4);
  float w2g[5][8], Gs[5], Bs[5], wrow[5];
  float t2_l = 0.f, g2_l = 0.f, be2_l = 0.f, validf = 0.f;
  float h2rep[5], pool_l = 0.f;
  int myrow = 0;
  float pf[2][8];
  const int gm   = (wave & 3) * 4 + q;
  const int goct = l15;
  const int gdst = gm * 128 + ((goct ^ gm) & 15) * 8;

  if (ln_role) {
    myrow = wave * 4 + q;
    int coct = (l15 ^ myrow) & 15;
#pragma unroll
    for (int j = 0; j < 8; j++) {
      int c = coct * 8 + j;
      float gc = g1[c];
#pragma unroll
      for (int jj = 0; jj < 5; jj++) w2g[jj][j] = Wih2[jj * DIM + c] * gc;
    }
#pragma unroll
    for (int jj = 0; jj < 5; jj++) { Gs[jj] = 0.f; Bs[jj] = 0.f; }
    for (int c = 0; c < DIM; c++) {
      float gc = g1[c], bc = be1[c];
#pragma unroll
      for (int jj = 0; jj < 5; jj++) {
        float w = Wih2[jj * DIM + c];
        Gs[jj] += w * gc; Bs[jj] += w * bc;
      }
    }
    validf = (l15 < 5) ? 1.f : 0.f;
    if (l15 < 5) {
      t2_l = bih2[l15] + bhh2[l15];
      g2_l = g2[l15]; be2_l = be2[l15];
#pragma unroll
      for (int jj = 0; jj < 5; jj++) wrow[jj] = Whh2[l15 * 5 + jj];
    } else {
#pragma unroll
      for (int jj = 0; jj < 5; jj++) wrow[jj] = 0.f;
    }
#pragma unroll
    for (int jj = 0; jj < 5; jj++) h2rep[jj] = 0.f;
  }
  __syncthreads();

  if (!ln_role) {
    float ta[8], tb[8];
    { int xid = x_tile[gm * 256 + 0];
      const float* pe = emb + (size_t)xid * DIM + goct * 8;
#pragma unroll
      for (int j = 0; j < 8; j++) ta[j] = pe[j]; }
    { int xid = x_tile[gm * 256 + 1];
      const float* pe = emb + (size_t)xid * DIM + goct * 8;
#pragma unroll
      for (int j = 0; j < 8; j++) tb[j] = pe[j]; }
    { int xid = x_tile[gm * 256 + 2];
      const float* pe = emb + (size_t)xid * DIM + goct * 8;
#pragma unroll
      for (int j = 0; j < 8; j++) pf[0][j] = pe[j]; }
    { int xid = x_tile[gm * 256 + 3];
      const float* pe = emb + (size_t)xid * DIM + goct * 8;
#pragma unroll
      for (int j = 0; j < 8; j++) pf[1][j] = pe[j]; }
    Frag8 pa, pb;
#pragma unroll
    for (int j = 0; j < 8; j++) { pa.us[j] = f2bf_bits(ta[j]); pb.us[j] = f2bf_bits(tb[j]); }
    *(int4*)&e_bf[0][gdst] = pa.i4;
    *(int4*)&e_bf[1][gdst] = pb.i4;
  }
  __syncthreads();

  f32x4 xpacc = {bias1v, bias1v, bias1v, bias1v};
#pragma unroll
  for (int kt = 0; kt < 4; kt++) {
    int sw = (((kt * 4 + q) ^ l15) & 15) * 8;
    bf16x8 ae = *(const bf16x8*)&e_bf[0][l15 * 128 + sw];
    xpacc = __builtin_amdgcn_mfma_f32_16x16x32_bf16(ae, wih[kt], xpacc, 0, 0, 0);
  }
  asm volatile("s_waitcnt lgkmcnt(0)\n\ts_barrier" ::: "memory");

#pragma unroll 2
  for (int t = 0; t <= S_LEN; t++) {
    f32x4 ah = {0.f, 0.f, 0.f, 0.f};
    f32x4 al = xpacc;
    if (t < S_LEN) {
      const int rb = (t + 1) & 1;
#pragma unroll
      for (int kt = 0; kt < 4; kt++) {
        int sw = (((kt * 4 + q) ^ l15) & 15) * 8;
        bf16x8 ahf = *(const bf16x8*)&h_bf[rb][l15 * 128 + sw];
        ah = __builtin_amdgcn_mfma_f32_16x16x32_bf16(ahf, whi[kt], ah, 0, 0, 0);
        al = __builtin_amdgcn_mfma_f32_16x16x32_bf16(ahf, wlo[kt], al, 0, 0, 0);
      }
    }
    if (t + 1 < S_LEN) {
      f32x4 a = {bias1v, bias1v, bias1v, bias1v};
#pragma unroll
      for (int kt = 0; kt < 4; kt++) {
        int sw = (((kt * 4 + q) ^ l15) & 15) * 8;
        bf16x8 ae = *(const bf16x8*)&e_bf[(t + 1) & 1][l15 * 128 + sw];
        a = __builtin_amdgcn_mfma_f32_16x16x32_bf16(ae, wih[kt], a, 0, 0, 0);
      }
      xpacc = a;
    }
    if (t < S_LEN) {
      const int wb = t & 1;
      const int c = wave * 16 + l15;
      const int oct = c >> 3;
#pragma unroll
      for (int r = 0; r < 4; r++) {
        int row = q * 4 + r;
        float av = ah[r] + al[r];
        h_bf[wb][row * 128 + ((oct ^ row) & 15) * 8 + (c & 7)] =
            (unsigned short)f2bf_rhu(tanh_fast(av));
      }
    }
    if (!ln_role) {
      if (t + 2 < S_LEN) {
        int4 pk;
        pk.x = pack_rhu(pf[t & 1][0], pf[t & 1][1]);
        pk.y = pack_rhu(pf[t & 1][2], pf[t & 1][3]);
        pk.z = pack_rhu(pf[t & 1][4], pf[t & 1][5]);
        pk.w = pack_rhu(pf[t & 1][6], pf[t & 1][7]);
        *(int4*)&e_bf[t & 1][gdst] = pk;
      }
      if (t + 4 < S_LEN) {
        int xid = x_tile[gm * 256 + t + 4];
        const float* pe = emb + (size_t)xid * DIM + goct * 8;
#pragma unroll
        for (int j = 0; j < 8; j++) pf[t & 1][j] = pe[j];
      }
    } else if (t >= 1) {
      const int hb = (t - 1) & 1;
      Frag8 hr;
      hr.i4 = *(const int4*)&h_bf[hb][myrow * 128 + l15 * 8];
      float s = 0.f, sq = 0.f, d[5] = {0, 0, 0, 0, 0};
#pragma unroll
      for (int j = 0; j < 8; j++) {
        float v = bf2f_bits(hr.us[j]);
        s += v; sq += v * v;
#pragma unroll
        for (int jj = 0; jj < 5; jj++) d[jj] = fmaf(w2g[jj][j], v, d[jj]);
      }
      red_level7<0x124>(s, sq, d);
      red_level7<0x128>(s, sq, d);
      red_level7<0x39>(s, sq, d);
      red_level7<0x4E>(s, sq, d);
      float mean = s * (1.f / 128.f);
      float var  = sq * (1.f / 128.f) - mean * mean;
      float rstd = rsqrtf(var + EPSL);
      float p[5];
#pragma unroll
      for (int jj = 0; jj < 5; jj++)
        p[jj] = rstd * (d[jj] - mean * Gs[jj]) + Bs[jj];
      float psel = (l15 == 0) ? p[0] : (l15 == 1) ? p[1] :
                   (l15 == 2) ? p[2] : (l15 == 3) ? p[3] : p[4];
      float a = psel + t2_l;
#pragma unroll
      for (int jj = 0; jj < 5; jj++) a = fmaf(wrow[jj], h2rep[jj], a);
      float xn = tanh_fast(a);
      h2rep[0] = bcast16<0>(xn); h2rep[1] = bcast16<1>(xn);
      h2rep[2] = bcast16<2>(xn); h2rep[3] = bcast16<3>(xn);
      h2rep[4] = bcast16<4>(xn);
      float s2 = dpp_sum16(xn * validf) * 0.2f;
      float dd = xn - s2;
      float v2 = dpp_sum16(dd * dd * validf) * 0.2f;
      float r2 = rsqrtf(v2 + EPSL);
      pool_l += dd * r2 * g2_l + be2_l;
    }
    asm volatile("s_waitcnt lgkmcnt(0)\n\ts_barrier" ::: "memory");
  }

  if (ln_role) {
    float lg = pool_l * (1.f / 256.f);
    float mx = dpp_max16((l15 < 5) ? lg : -3.0e38f);
    float e  = (l15 < 5) ? __expf(lg - mx) : 0.f;
    float sm = dpp_sum16(e);
    if (l15 < 5) out[(size_t)(r0 + myrow) * 5 + l15] = e / sm;
  }
}

extern "C" void kernel_launch(void* const* d_in, const int* in_sizes, int n_in,
                              void* d_out, int out_size, void* d_ws, size_t ws_size,
                              hipStream_t stream) {
  (void)in_sizes; (void)n_in; (void)out_size;
  const int*   x    = (const int*)  d_in[0];
  const float* emb  = (const float*)d_in[1];
  const float* Wih1 = (const float*)d_in[2];
  const float* bih1 = (const float*)d_in[3];
  const float* Whh1 = (const float*)d_in[4];
  const float* bhh1 = (const float*)d_in[5];
  const float* g1   = (const float*)d_in[6];
  const float* be1  = (const float*)d_in[7];
  const float* Wih2 = (const float*)d_in[8];
  const float* bih2 = (const float*)d_in[9];
  const float* Whh2 = (const float*)d_in[10];
  const float* bhh2 = (const float*)d_in[11];
  const float* g2   = (const float*)d_in[12];
  const float* be2  = (const float*)d_in[13];
  float* out = (float*)d_out;

  const size_t XPBYTES = (size_t)S_LEN * 64 * 128 * 16 * 2;   // 64 MiB bf16
  if (ws_size >= XPBYTES) {
    unsigned short* ws = (unsigned short*)d_ws;
    xproj_pre<<<dim3(1024), dim3(512), 0, stream>>>(x, emb, Wih1, bih1, bhh1, ws);
    rnn_serial<<<dim3(64), dim3(512), 0, stream>>>(ws, Whh1, g1, be1, Wih2,
                                                   bih2, Whh2, bhh2, g2, be2, out);
  } else {
    rnn_fused_fb<<<dim3(64), dim3(512), 0, stream>>>(
        x, emb, Wih1, bih1, Whh1, bhh1, g1, be1,
        Wih2, bih2, Whh2, bhh2, g2, be2, out);
  }
}

// Round 8
// 316.153 us; speedup vs baseline: 1.0099x; 1.0099x over previous
//
#include <hip/hip_runtime.h>
#include <stdint.h>

#define S_LEN 256
#define DIM   128
#define EPSL  1e-5f

typedef __bf16 bf16x8 __attribute__((ext_vector_type(8)));
typedef float  f32x4  __attribute__((ext_vector_type(4)));

__device__ __forceinline__ unsigned short f2bf_bits(float f) {
  union { float f; unsigned int u; } v; v.f = f;
  unsigned int r = v.u + 0x7fffu + ((v.u >> 16) & 1u);   // RTNE (init paths)
  return (unsigned short)(r >> 16);
}
__device__ __forceinline__ float bf2f_bits(unsigned short b) {
  union { float f; unsigned int u; } v; v.u = ((unsigned int)b) << 16; return v.f;
}
// Hot-path bf16 round-half-up: 2 VALU ops.
__device__ __forceinline__ unsigned f2bf_rhu(float f) {
  return (__float_as_uint(f) + 0x8000u) >> 16;
}
// Pack two floats -> (bf16 lo, bf16 hi) in one u32: 2 adds + 1 v_perm.
__device__ __forceinline__ unsigned pack_rhu(float lo, float hi) {
  return __builtin_amdgcn_perm(__float_as_uint(hi) + 0x8000u,
                               __float_as_uint(lo) + 0x8000u, 0x07060302u);
}
// tanh(x) = 1 - 2/(e^{2x}+1): ~1e-6 rel err, exact at +-inf.
__device__ __forceinline__ float tanh_fast(float x) {
  float e = __expf(2.f * x);
  return 1.f - 2.f * __builtin_amdgcn_rcpf(e + 1.f);
}

// VALU cross-lane via DPP rotation; 16-lane reduce visible on all lanes.
template<int CTRL>
__device__ __forceinline__ float dpp_rot_add(float v) {
  int r = __builtin_amdgcn_update_dpp(0, __float_as_int(v), CTRL, 0xF, 0xF, true);
  return v + __int_as_float(r);
}
template<int CTRL>
__device__ __forceinline__ float dpp_rot_max(float v) {
  int r = __builtin_amdgcn_update_dpp(0, __float_as_int(v), CTRL, 0xF, 0xF, true);
  return fmaxf(v, __int_as_float(r));
}
__device__ __forceinline__ float dpp_sum16(float v) {
  v = dpp_rot_add<0x124>(v); v = dpp_rot_add<0x128>(v);
  v = dpp_rot_add<0x39>(v);  v = dpp_rot_add<0x4E>(v);
  return v;
}
__device__ __forceinline__ float dpp_max16(float v) {
  v = dpp_rot_max<0x124>(v); v = dpp_rot_max<0x128>(v);
  v = dpp_rot_max<0x39>(v);  v = dpp_rot_max<0x4E>(v);
  return v;
}
template<int CTRL>
__device__ __forceinline__ void red_level7(float& s, float& sq, float* d) {
  s  = dpp_rot_add<CTRL>(s);
  sq = dpp_rot_add<CTRL>(sq);
#pragma unroll
  for (int j = 0; j < 5; j++) d[j] = dpp_rot_add<CTRL>(d[j]);
}
template<int JJ>
__device__ __forceinline__ float bcast16(float v) {
  int r = __builtin_amdgcn_ds_swizzle(__float_as_int(v), (JJ << 5) | 0x10);
  return __int_as_float(r);
}

union Frag8 { unsigned short us[8]; bf16x8 v; int4 i4; };

// Fused single kernel (R6 structure + chain surgery):
// 8 homogeneous core waves, each owns n-tile [wave*16, wave*16+16).
// Per step: 4 independent depth-2 MFMA chains (h@Whh hi/lo split) + 4-tanh
// epilogue; e@Wih for t+1 computed off-path into registers (depth-2 chains).
// Waves 0-3 also do LN1/RNN2/LN2/pool (h-read hoisted to interval top,
// h2-broadcasts sunk below pool); waves 4-7 also do e-gather/staging.
// s_setprio elevates the serial core section. One raw lgkm barrier per step.
__global__ __launch_bounds__(512, 2)
void rnn_fused(const int* __restrict__ x, const float* __restrict__ emb,
               const float* __restrict__ Wih1, const float* __restrict__ bih1,
               const float* __restrict__ Whh1, const float* __restrict__ bhh1,
               const float* __restrict__ g1, const float* __restrict__ be1,
               const float* __restrict__ Wih2, const float* __restrict__ bih2,
               const float* __restrict__ Whh2, const float* __restrict__ bhh2,
               const float* __restrict__ g2, const float* __restrict__ be2,
               float* __restrict__ out)
{
  // h/e element (row m, channel c) at m*128 + ((c>>3) ^ (m&15))*8 + (c&7)
  __shared__ __align__(16) unsigned short h_bf[2][16 * 128];   // 8 KB
  __shared__ __align__(16) unsigned short e_bf[2][16 * 128];   // 8 KB
  __shared__ int x_tile[16 * 256];                             // 16 KB

  const int tid  = threadIdx.x;
  const int wave = tid >> 6;
  const int lane = tid & 63;
  const int r0   = blockIdx.x * 16;
  const int l15  = lane & 15;
  const int q    = lane >> 4;

  for (int i = tid; i < 16 * 256; i += 512)
    x_tile[i] = x[(size_t)(r0 + (i >> 8)) * S_LEN + (i & 255)];
  for (int i = tid; i < 16 * 128; i += 512) h_bf[1][i] = 0;   // h_{-1} = 0

  const int n1 = wave * 16 + l15;
  const float bias1v = bih1[n1] + bhh1[n1];
  bf16x8 whi[4], wlo[4], wih[4];
#pragma unroll
  for (int kt = 0; kt < 4; kt++) {
    int k0 = kt * 32 + q * 8;
    Frag8 fh, fl, fa;
#pragma unroll
    for (int j = 0; j < 8; j++) {
      float w = Whh1[n1 * DIM + k0 + j];
      unsigned short hi = f2bf_bits(w);
      fh.us[j] = hi;
      fl.us[j] = f2bf_bits(w - bf2f_bits(hi));     // split-bf16 compensation
      fa.us[j] = f2bf_bits(Wih1[n1 * DIM + k0 + j]);
    }
    whi[kt] = fh.v; wlo[kt] = fl.v; wih[kt] = fa.v;
  }

  const bool ln_role = (wave < 4);
  float w2g[5][8], Gs[5], Bs[5], wrow[5];
  float t2_l = 0.f, g2_l = 0.f, be2_l = 0.f, validf = 0.f;
  float h2rep[5], pool_l = 0.f;
  int myrow = 0;
  float pf[2][8];
  const int gm   = (wave & 3) * 4 + q;   // staging row (waves 4-7)
  const int goct = l15;
  const int gdst = gm * 128 + ((goct ^ gm) & 15) * 8;

  if (ln_role) {
    myrow = wave * 4 + q;
    int coct = (l15 ^ myrow) & 15;       // storage oct l15 -> channels coct*8..+7
#pragma unroll
    for (int j = 0; j < 8; j++) {
      int c = coct * 8 + j;
      float gc = g1[c];
#pragma unroll
      for (int jj = 0; jj < 5; jj++) w2g[jj][j] = Wih2[jj * DIM + c] * gc;
    }
#pragma unroll
    for (int jj = 0; jj < 5; jj++) { Gs[jj] = 0.f; Bs[jj] = 0.f; }
    for (int c = 0; c < DIM; c++) {      // init-only scalar loop
      float gc = g1[c], bc = be1[c];
#pragma unroll
      for (int jj = 0; jj < 5; jj++) {
        float w = Wih2[jj * DIM + c];
        Gs[jj] += w * gc; Bs[jj] += w * bc;
      }
    }
    validf = (l15 < 5) ? 1.f : 0.f;
    if (l15 < 5) {
      t2_l = bih2[l15] + bhh2[l15];
      g2_l = g2[l15]; be2_l = be2[l15];
#pragma unroll
      for (int jj = 0; jj < 5; jj++) wrow[jj] = Whh2[l15 * 5 + jj];
    } else {
#pragma unroll
      for (int jj = 0; jj < 5; jj++) wrow[jj] = 0.f;
    }
#pragma unroll
    for (int jj = 0; jj < 5; jj++) h2rep[jj] = 0.f;
  }
  __syncthreads();

  if (!ln_role) {                        // stage e[0],e[1]; preload pf=e[2],e[3]
    float ta[8], tb[8];
    { int xid = x_tile[gm * 256 + 0];
      const float* pe = emb + (size_t)xid * DIM + goct * 8;
#pragma unroll
      for (int j = 0; j < 8; j++) ta[j] = pe[j]; }
    { int xid = x_tile[gm * 256 + 1];
      const float* pe = emb + (size_t)xid * DIM + goct * 8;
#pragma unroll
      for (int j = 0; j < 8; j++) tb[j] = pe[j]; }
    { int xid = x_tile[gm * 256 + 2];
      const float* pe = emb + (size_t)xid * DIM + goct * 8;
#pragma unroll
      for (int j = 0; j < 8; j++) pf[0][j] = pe[j]; }
    { int xid = x_tile[gm * 256 + 3];
      const float* pe = emb + (size_t)xid * DIM + goct * 8;
#pragma unroll
      for (int j = 0; j < 8; j++) pf[1][j] = pe[j]; }
    Frag8 pa, pb;
#pragma unroll
    for (int j = 0; j < 8; j++) { pa.us[j] = f2bf_bits(ta[j]); pb.us[j] = f2bf_bits(tb[j]); }
    *(int4*)&e_bf[0][gdst] = pa.i4;
    *(int4*)&e_bf[1][gdst] = pb.i4;
  }
  __syncthreads();

  // xpacc = e[0]@Wih^T + bias for this wave's n-tile (register handoff)
  f32x4 xpacc = {bias1v, bias1v, bias1v, bias1v};
#pragma unroll
  for (int kt = 0; kt < 4; kt++) {
    int sw = (((kt * 4 + q) ^ l15) & 15) * 8;
    bf16x8 ae = *(const bf16x8*)&e_bf[0][l15 * 128 + sw];
    xpacc = __builtin_amdgcn_mfma_f32_16x16x32_bf16(ae, wih[kt], xpacc, 0, 0, 0);
  }
  asm volatile("s_waitcnt lgkmcnt(0)\n\ts_barrier" ::: "memory");

#pragma unroll 2
  for (int t = 0; t <= S_LEN; t++) {
    // LN h-read hoisted to interval top: hides LDS latency under core work.
    Frag8 hr;
    const bool do_ln = ln_role && (t >= 1) && (t <= S_LEN);
    if (do_ln)
      hr.i4 = *(const int4*)&h_bf[(t - 1) & 1][myrow * 128 + l15 * 8];

    asm volatile("s_setprio 1" :::);     // serial core section: win issue arb
    // 4 independent depth-2 MFMA chains (was 2 chains of depth 4)
    f32x4 ah_a = {0.f, 0.f, 0.f, 0.f}, ah_b = {0.f, 0.f, 0.f, 0.f};
    f32x4 al_a = xpacc,                 al_b = {0.f, 0.f, 0.f, 0.f};
    if (t < S_LEN) {
      const int rb = (t + 1) & 1;        // h_{t-1}
#pragma unroll
      for (int kt = 0; kt < 4; kt++) {
        int sw = (((kt * 4 + q) ^ l15) & 15) * 8;
        bf16x8 ahf = *(const bf16x8*)&h_bf[rb][l15 * 128 + sw];
        if (kt < 2) {
          ah_a = __builtin_amdgcn_mfma_f32_16x16x32_bf16(ahf, whi[kt], ah_a, 0, 0, 0);
          al_a = __builtin_amdgcn_mfma_f32_16x16x32_bf16(ahf, wlo[kt], al_a, 0, 0, 0);
        } else {
          ah_b = __builtin_amdgcn_mfma_f32_16x16x32_bf16(ahf, whi[kt], ah_b, 0, 0, 0);
          al_b = __builtin_amdgcn_mfma_f32_16x16x32_bf16(ahf, wlo[kt], al_b, 0, 0, 0);
        }
      }
      const int wb = t & 1;
      const int c = n1;
      const int oct = c >> 3;
#pragma unroll
      for (int r = 0; r < 4; r++) {      // D-layout: row = q*4 + r, col = l15
        int row = q * 4 + r;
        float av = (ah_a[r] + al_a[r]) + (ah_b[r] + al_b[r]);
        h_bf[wb][row * 128 + ((oct ^ row) & 15) * 8 + (c & 7)] =
            (unsigned short)f2bf_rhu(tanh_fast(av));
      }
    }
    asm volatile("s_setprio 0" :::);     // side roles: lower priority

    if (t + 1 < S_LEN) {                 // e_{t+1}@Wih into regs, 2 chains
      f32x4 ea = {bias1v, bias1v, bias1v, bias1v};
      f32x4 eb = {0.f, 0.f, 0.f, 0.f};
#pragma unroll
      for (int kt = 0; kt < 4; kt++) {
        int sw = (((kt * 4 + q) ^ l15) & 15) * 8;
        bf16x8 ae = *(const bf16x8*)&e_bf[(t + 1) & 1][l15 * 128 + sw];
        if (kt < 2)
          ea = __builtin_amdgcn_mfma_f32_16x16x32_bf16(ae, wih[kt], ea, 0, 0, 0);
        else
          eb = __builtin_amdgcn_mfma_f32_16x16x32_bf16(ae, wih[kt], eb, 0, 0, 0);
      }
#pragma unroll
      for (int r = 0; r < 4; r++) xpacc[r] = ea[r] + eb[r];
    }

    if (!ln_role) {                      // staging role (waves 4-7)
      if (t + 2 < S_LEN) {               // stage e[t+2] (gathered at t-2)
        int4 pk;
        pk.x = pack_rhu(pf[t & 1][0], pf[t & 1][1]);
        pk.y = pack_rhu(pf[t & 1][2], pf[t & 1][3]);
        pk.z = pack_rhu(pf[t & 1][4], pf[t & 1][5]);
        pk.w = pack_rhu(pf[t & 1][6], pf[t & 1][7]);
        *(int4*)&e_bf[t & 1][gdst] = pk;
      }
      if (t + 4 < S_LEN) {               // issue gather e[t+4] (2-step cover)
        int xid = x_tile[gm * 256 + t + 4];
        const float* pe = emb + (size_t)xid * DIM + goct * 8;
#pragma unroll
        for (int j = 0; j < 8; j++) pf[t & 1][j] = pe[j];
      }
    } else if (do_ln) {                  // LN role (waves 0-3) on h_{t-1}
      float s = 0.f, sq = 0.f, d[5] = {0, 0, 0, 0, 0};
#pragma unroll
      for (int j = 0; j < 8; j++) {
        float v = bf2f_bits(hr.us[j]);
        s += v; sq += v * v;
#pragma unroll
        for (int jj = 0; jj < 5; jj++) d[jj] = fmaf(w2g[jj][j], v, d[jj]);
      }
      red_level7<0x124>(s, sq, d);       // one 4-level DPP butterfly, 7 values
      red_level7<0x128>(s, sq, d);
      red_level7<0x39>(s, sq, d);
      red_level7<0x4E>(s, sq, d);
      float mean = s * (1.f / 128.f);
      float var  = sq * (1.f / 128.f) - mean * mean;
      float rstd = rsqrtf(var + EPSL);
      float p[5];
#pragma unroll
      for (int jj = 0; jj < 5; jj++)     // exact fold of LN1+proj
        p[jj] = rstd * (d[jj] - mean * Gs[jj]) + Bs[jj];
      float psel = (l15 == 0) ? p[0] : (l15 == 1) ? p[1] :
                   (l15 == 2) ? p[2] : (l15 == 3) ? p[3] : p[4];
      float a = psel + t2_l;
#pragma unroll
      for (int jj = 0; jj < 5; jj++) a = fmaf(wrow[jj], h2rep[jj], a);
      float xn = tanh_fast(a);           // one tanh issue for all 5 dims
      float s2 = dpp_sum16(xn * validf) * 0.2f;        // mean over 5
      float dd = xn - s2;
      float v2 = dpp_sum16(dd * dd * validf) * 0.2f;   // var over 5
      float r2 = rsqrtf(v2 + EPSL);
      pool_l += dd * r2 * g2_l + be2_l;  // valid only l15<5
      // h2 broadcasts sunk below pool: results only needed next step.
      h2rep[0] = bcast16<0>(xn); h2rep[1] = bcast16<1>(xn);
      h2rep[2] = bcast16<2>(xn); h2rep[3] = bcast16<3>(xn);
      h2rep[4] = bcast16<4>(xn);
    }
    // Raw barrier: drain LDS only; global gather loads stay in flight.
    asm volatile("s_waitcnt lgkmcnt(0)\n\ts_barrier" ::: "memory");
  }

  if (ln_role) {                         // softmax over the 5 pool lanes
    float lg = pool_l * (1.f / 256.f);
    float mx = dpp_max16((l15 < 5) ? lg : -3.0e38f);
    float e  = (l15 < 5) ? __expf(lg - mx) : 0.f;
    float sm = dpp_sum16(e);
    if (l15 < 5) out[(size_t)(r0 + myrow) * 5 + l15] = e / sm;
  }
}

extern "C" void kernel_launch(void* const* d_in, const int* in_sizes, int n_in,
                              void* d_out, int out_size, void* d_ws, size_t ws_size,
                              hipStream_t stream) {
  (void)in_sizes; (void)n_in; (void)d_ws; (void)ws_size; (void)out_size;
  rnn_fused<<<dim3(64), dim3(512), 0, stream>>>(
      (const int*)  d_in[0],  (const float*)d_in[1],  (const float*)d_in[2],
      (const float*)d_in[3],  (const float*)d_in[4],  (const float*)d_in[5],
      (const float*)d_in[6],  (const float*)d_in[7],  (const float*)d_in[8],
      (const float*)d_in[9],  (const float*)d_in[10], (const float*)d_in[11],
      (const float*)d_in[12], (const float*)d_in[13], (float*)d_out);
}

// Round 9
// 281.298 us; speedup vs baseline: 1.1350x; 1.1239x over previous
//
#include <hip/hip_runtime.h>
#include <stdint.h>

#define S_LEN 256
#define DIM   128
#define EPSL  1e-5f

typedef __bf16 bf16x8 __attribute__((ext_vector_type(8)));
typedef float  f32x4  __attribute__((ext_vector_type(4)));

__device__ __forceinline__ unsigned short f2bf_bits(float f) {
  union { float f; unsigned int u; } v; v.f = f;
  unsigned int r = v.u + 0x7fffu + ((v.u >> 16) & 1u);   // RTNE (init paths)
  return (unsigned short)(r >> 16);
}
__device__ __forceinline__ float bf2f_bits(unsigned short b) {
  union { float f; unsigned int u; } v; v.u = ((unsigned int)b) << 16; return v.f;
}
// Hot-path bf16 round-half-up: 2 VALU ops.
__device__ __forceinline__ unsigned f2bf_rhu(float f) {
  return (__float_as_uint(f) + 0x8000u) >> 16;
}
// Pack two floats -> (bf16 lo, bf16 hi) in one u32: 2 adds + 1 v_perm.
__device__ __forceinline__ unsigned pack_rhu(float lo, float hi) {
  return __builtin_amdgcn_perm(__float_as_uint(hi) + 0x8000u,
                               __float_as_uint(lo) + 0x8000u, 0x07060302u);
}
// tanh(x) = 1 - 2/(e^{2x}+1): ~1e-6 rel err, exact at +-inf.
__device__ __forceinline__ float tanh_fast(float x) {
  float e = __expf(2.f * x);
  return 1.f - 2.f * __builtin_amdgcn_rcpf(e + 1.f);
}

// VALU cross-lane via DPP rotation; 16-lane reduce visible on all lanes.
template<int CTRL>
__device__ __forceinline__ float dpp_rot_add(float v) {
  int r = __builtin_amdgcn_update_dpp(0, __float_as_int(v), CTRL, 0xF, 0xF, true);
  return v + __int_as_float(r);
}
template<int CTRL>
__device__ __forceinline__ float dpp_rot_max(float v) {
  int r = __builtin_amdgcn_update_dpp(0, __float_as_int(v), CTRL, 0xF, 0xF, true);
  return fmaxf(v, __int_as_float(r));
}
__device__ __forceinline__ float dpp_sum16(float v) {
  v = dpp_rot_add<0x124>(v); v = dpp_rot_add<0x128>(v);
  v = dpp_rot_add<0x39>(v);  v = dpp_rot_add<0x4E>(v);
  return v;
}
__device__ __forceinline__ float dpp_max16(float v) {
  v = dpp_rot_max<0x124>(v); v = dpp_rot_max<0x128>(v);
  v = dpp_rot_max<0x39>(v);  v = dpp_rot_max<0x4E>(v);
  return v;
}
template<int CTRL>
__device__ __forceinline__ void red_level7(float& s, float& sq, float* d) {
  s  = dpp_rot_add<CTRL>(s);
  sq = dpp_rot_add<CTRL>(sq);
#pragma unroll
  for (int j = 0; j < 5; j++) d[j] = dpp_rot_add<CTRL>(d[j]);
}
template<int JJ>
__device__ __forceinline__ float bcast16(float v) {
  int r = __builtin_amdgcn_ds_swizzle(__float_as_int(v), (JJ << 5) | 0x10);
  return __int_as_float(r);
}

union Frag8 { unsigned short us[8]; bf16x8 v; int4 i4; };

// R6 structure, lo-compensation dropped: 8 homogeneous core waves, each owns
// n-tile [wave*16, wave*16+16). Per step: ONE depth-4 MFMA chain (h@Whh bf16,
// acc seeded with e-proj xpacc) + 4-tanh epilogue; e@Wih for t+1 off-path into
// registers. Waves 0-3: LN1/RNN2/LN2/pool; waves 4-7: e-gather/staging.
// One raw lgkm-only barrier per step.
__global__ __launch_bounds__(512, 2)
void rnn_fused(const int* __restrict__ x, const float* __restrict__ emb,
               const float* __restrict__ Wih1, const float* __restrict__ bih1,
               const float* __restrict__ Whh1, const float* __restrict__ bhh1,
               const float* __restrict__ g1, const float* __restrict__ be1,
               const float* __restrict__ Wih2, const float* __restrict__ bih2,
               const float* __restrict__ Whh2, const float* __restrict__ bhh2,
               const float* __restrict__ g2, const float* __restrict__ be2,
               float* __restrict__ out)
{
  // h/e element (row m, channel c) at m*128 + ((c>>3) ^ (m&15))*8 + (c&7)
  __shared__ __align__(16) unsigned short h_bf[2][16 * 128];   // 8 KB
  __shared__ __align__(16) unsigned short e_bf[2][16 * 128];   // 8 KB
  __shared__ int x_tile[16 * 256];                             // 16 KB

  const int tid  = threadIdx.x;
  const int wave = tid >> 6;
  const int lane = tid & 63;
  const int r0   = blockIdx.x * 16;
  const int l15  = lane & 15;
  const int q    = lane >> 4;

  for (int i = tid; i < 16 * 256; i += 512)
    x_tile[i] = x[(size_t)(r0 + (i >> 8)) * S_LEN + (i & 255)];
  for (int i = tid; i < 16 * 128; i += 512) h_bf[1][i] = 0;   // h_{-1} = 0

  const int n1 = wave * 16 + l15;
  const float bias1v = bih1[n1] + bhh1[n1];
  bf16x8 wh[4], wih[4];
#pragma unroll
  for (int kt = 0; kt < 4; kt++) {
    int k0 = kt * 32 + q * 8;
    Frag8 fh, fa;
#pragma unroll
    for (int j = 0; j < 8; j++) {
      fh.us[j] = f2bf_bits(Whh1[n1 * DIM + k0 + j]);   // bf16-only Whh
      fa.us[j] = f2bf_bits(Wih1[n1 * DIM + k0 + j]);
    }
    wh[kt] = fh.v; wih[kt] = fa.v;
  }

  const bool ln_role = (wave < 4);
  float w2g[5][8], Gs[5], Bs[5], wrow[5];
  float t2_l = 0.f, g2_l = 0.f, be2_l = 0.f, validf = 0.f;
  float h2rep[5], pool_l = 0.f;
  int myrow = 0;
  float pf[2][8];
  const int gm   = (wave & 3) * 4 + q;   // staging row (waves 4-7)
  const int goct = l15;
  const int gdst = gm * 128 + ((goct ^ gm) & 15) * 8;

  if (ln_role) {
    myrow = wave * 4 + q;
    int coct = (l15 ^ myrow) & 15;       // storage oct l15 -> channels coct*8..+7
#pragma unroll
    for (int j = 0; j < 8; j++) {
      int c = coct * 8 + j;
      float gc = g1[c];
#pragma unroll
      for (int jj = 0; jj < 5; jj++) w2g[jj][j] = Wih2[jj * DIM + c] * gc;
    }
#pragma unroll
    for (int jj = 0; jj < 5; jj++) { Gs[jj] = 0.f; Bs[jj] = 0.f; }
    for (int c = 0; c < DIM; c++) {      // init-only scalar loop
      float gc = g1[c], bc = be1[c];
#pragma unroll
      for (int jj = 0; jj < 5; jj++) {
        float w = Wih2[jj * DIM + c];
        Gs[jj] += w * gc; Bs[jj] += w * bc;
      }
    }
    validf = (l15 < 5) ? 1.f : 0.f;
    if (l15 < 5) {
      t2_l = bih2[l15] + bhh2[l15];
      g2_l = g2[l15]; be2_l = be2[l15];
#pragma unroll
      for (int jj = 0; jj < 5; jj++) wrow[jj] = Whh2[l15 * 5 + jj];
    } else {
#pragma unroll
      for (int jj = 0; jj < 5; jj++) wrow[jj] = 0.f;
    }
#pragma unroll
    for (int jj = 0; jj < 5; jj++) h2rep[jj] = 0.f;
  }
  __syncthreads();

  if (!ln_role) {                        // stage e[0],e[1]; preload pf=e[2],e[3]
    float ta[8], tb[8];
    { int xid = x_tile[gm * 256 + 0];
      const float* pe = emb + (size_t)xid * DIM + goct * 8;
#pragma unroll
      for (int j = 0; j < 8; j++) ta[j] = pe[j]; }
    { int xid = x_tile[gm * 256 + 1];
      const float* pe = emb + (size_t)xid * DIM + goct * 8;
#pragma unroll
      for (int j = 0; j < 8; j++) tb[j] = pe[j]; }
    { int xid = x_tile[gm * 256 + 2];
      const float* pe = emb + (size_t)xid * DIM + goct * 8;
#pragma unroll
      for (int j = 0; j < 8; j++) pf[0][j] = pe[j]; }
    { int xid = x_tile[gm * 256 + 3];
      const float* pe = emb + (size_t)xid * DIM + goct * 8;
#pragma unroll
      for (int j = 0; j < 8; j++) pf[1][j] = pe[j]; }
    Frag8 pa, pb;
#pragma unroll
    for (int j = 0; j < 8; j++) { pa.us[j] = f2bf_bits(ta[j]); pb.us[j] = f2bf_bits(tb[j]); }
    *(int4*)&e_bf[0][gdst] = pa.i4;
    *(int4*)&e_bf[1][gdst] = pb.i4;
  }
  __syncthreads();

  // xpacc = e[0]@Wih^T + bias for this wave's n-tile (register handoff)
  f32x4 xpacc = {bias1v, bias1v, bias1v, bias1v};
#pragma unroll
  for (int kt = 0; kt < 4; kt++) {
    int sw = (((kt * 4 + q) ^ l15) & 15) * 8;
    bf16x8 ae = *(const bf16x8*)&e_bf[0][l15 * 128 + sw];
    xpacc = __builtin_amdgcn_mfma_f32_16x16x32_bf16(ae, wih[kt], xpacc, 0, 0, 0);
  }
  asm volatile("s_waitcnt lgkmcnt(0)\n\ts_barrier" ::: "memory");

#pragma unroll 2
  for (int t = 0; t <= S_LEN; t++) {
    // ---- serial core: acc seeded with xpacc, ONE depth-4 chain ----
    f32x4 acc = xpacc;
    if (t < S_LEN) {
      const int rb = (t + 1) & 1;        // h_{t-1}
#pragma unroll
      for (int kt = 0; kt < 4; kt++) {
        int sw = (((kt * 4 + q) ^ l15) & 15) * 8;
        bf16x8 ahf = *(const bf16x8*)&h_bf[rb][l15 * 128 + sw];
        acc = __builtin_amdgcn_mfma_f32_16x16x32_bf16(ahf, wh[kt], acc, 0, 0, 0);
      }
      const int wb = t & 1;
      const int c = n1;
      const int oct = c >> 3;
#pragma unroll
      for (int r = 0; r < 4; r++) {      // D-layout: row = q*4 + r, col = l15
        int row = q * 4 + r;
        h_bf[wb][row * 128 + ((oct ^ row) & 15) * 8 + (c & 7)] =
            (unsigned short)f2bf_rhu(tanh_fast(acc[r]));
      }
    }

    if (t + 1 < S_LEN) {                 // e_{t+1}@Wih into regs (off-chain)
      f32x4 a = {bias1v, bias1v, bias1v, bias1v};
#pragma unroll
      for (int kt = 0; kt < 4; kt++) {
        int sw = (((kt * 4 + q) ^ l15) & 15) * 8;
        bf16x8 ae = *(const bf16x8*)&e_bf[(t + 1) & 1][l15 * 128 + sw];
        a = __builtin_amdgcn_mfma_f32_16x16x32_bf16(ae, wih[kt], a, 0, 0, 0);
      }
      xpacc = a;
    }

    if (!ln_role) {                      // ---- staging role (waves 4-7)
      if (t + 2 < S_LEN) {               // stage e[t+2] (gathered at t-2)
        int4 pk;
        pk.x = pack_rhu(pf[t & 1][0], pf[t & 1][1]);
        pk.y = pack_rhu(pf[t & 1][2], pf[t & 1][3]);
        pk.z = pack_rhu(pf[t & 1][4], pf[t & 1][5]);
        pk.w = pack_rhu(pf[t & 1][6], pf[t & 1][7]);
        *(int4*)&e_bf[t & 1][gdst] = pk;
      }
      if (t + 4 < S_LEN) {               // issue gather e[t+4] (2-step cover)
        int xid = x_tile[gm * 256 + t + 4];
        const float* pe = emb + (size_t)xid * DIM + goct * 8;
#pragma unroll
        for (int j = 0; j < 8; j++) pf[t & 1][j] = pe[j];
      }
    } else if (t >= 1) {                 // ---- LN role (waves 0-3) on h_{t-1}
      const int hb = (t - 1) & 1;
      Frag8 hr;
      hr.i4 = *(const int4*)&h_bf[hb][myrow * 128 + l15 * 8];
      float s = 0.f, sq = 0.f, d[5] = {0, 0, 0, 0, 0};
#pragma unroll
      for (int j = 0; j < 8; j++) {
        float v = bf2f_bits(hr.us[j]);
        s += v; sq += v * v;
#pragma unroll
        for (int jj = 0; jj < 5; jj++) d[jj] = fmaf(w2g[jj][j], v, d[jj]);
      }
      red_level7<0x124>(s, sq, d);       // one 4-level DPP butterfly, 7 values
      red_level7<0x128>(s, sq, d);
      red_level7<0x39>(s, sq, d);
      red_level7<0x4E>(s, sq, d);
      float mean = s * (1.f / 128.f);
      float var  = sq * (1.f / 128.f) - mean * mean;
      float rstd = rsqrtf(var + EPSL);
      float p[5];
#pragma unroll
      for (int jj = 0; jj < 5; jj++)     // exact fold of LN1+proj
        p[jj] = rstd * (d[jj] - mean * Gs[jj]) + Bs[jj];
      float psel = (l15 == 0) ? p[0] : (l15 == 1) ? p[1] :
                   (l15 == 2) ? p[2] : (l15 == 3) ? p[3] : p[4];
      float a = psel + t2_l;
#pragma unroll
      for (int jj = 0; jj < 5; jj++) a = fmaf(wrow[jj], h2rep[jj], a);
      float xn = tanh_fast(a);           // one tanh issue for all 5 dims
      float s2 = dpp_sum16(xn * validf) * 0.2f;        // mean over 5
      float dd = xn - s2;
      float v2 = dpp_sum16(dd * dd * validf) * 0.2f;   // var over 5
      float r2 = rsqrtf(v2 + EPSL);
      pool_l += dd * r2 * g2_l + be2_l;  // valid only l15<5
      h2rep[0] = bcast16<0>(xn); h2rep[1] = bcast16<1>(xn);
      h2rep[2] = bcast16<2>(xn); h2rep[3] = bcast16<3>(xn);
      h2rep[4] = bcast16<4>(xn);
    }
    // Raw barrier: drain LDS only; global gather loads stay in flight.
    asm volatile("s_waitcnt lgkmcnt(0)\n\ts_barrier" ::: "memory");
  }

  if (ln_role) {                         // softmax over the 5 pool lanes
    float lg = pool_l * (1.f / 256.f);
    float mx = dpp_max16((l15 < 5) ? lg : -3.0e38f);
    float e  = (l15 < 5) ? __expf(lg - mx) : 0.f;
    float sm = dpp_sum16(e);
    if (l15 < 5) out[(size_t)(r0 + myrow) * 5 + l15] = e / sm;
  }
}

extern "C" void kernel_launch(void* const* d_in, const int* in_sizes, int n_in,
                              void* d_out, int out_size, void* d_ws, size_t ws_size,
                              hipStream_t stream) {
  (void)in_sizes; (void)n_in; (void)d_ws; (void)ws_size; (void)out_size;
  rnn_fused<<<dim3(64), dim3(512), 0, stream>>>(
      (const int*)  d_in[0],  (const float*)d_in[1],  (const float*)d_in[2],
      (const float*)d_in[3],  (const float*)d_in[4],  (const float*)d_in[5],
      (const float*)d_in[6],  (const float*)d_in[7],  (const float*)d_in[8],
      (const float*)d_in[9],  (const float*)d_in[10], (const float*)d_in[11],
      (const float*)d_in[12], (const float*)d_in[13], (float*)d_out);
}